// Round 8
// baseline (220.906 us; speedup 1.0000x reference)
//
#include <hip/hip_runtime.h>

// EIT3Attention: B=4, Sq=Sk=2048, d_model=2048, H=16, Dh=128, fp32 I/O.
// R8: NO-LDS main kernel. Prepass dequants K/V -> bf16 ws in EXACT
// MFMA-fragment order (per 32-row tile: frag x lane x 8elems), so the main
// kernel loads fragments register-direct via coalesced 16B/lane global loads
// (L2-resident; 16 q-blocks/bh share streams). Removes all ds_read/ds_write,
// all bank conflicts, and all in-loop barriers (R7 diagnosis: LDS pipe ~52%
// of cycles + barrier lockstep at 2 waves/SIMD). 2-step-unrolled K prefetch.

typedef __attribute__((ext_vector_type(8))) short short8;
typedef __attribute__((ext_vector_type(16))) float f32x16;

#define DEVI __device__ __forceinline__

namespace {

constexpr int DM = 2048;   // d_model
constexpr int SQ = 2048;
constexpr int SK = 2048;
constexpr int DH = 128;
constexpr int KVB = 32;            // kv rows per tile
constexpr int NT = SK / KVB;       // 64 tiles
constexpr int TILE_E = KVB * DH;   // 4096 elems per tensor-tile
// (1/sqrt(128)) * log2(e)
constexpr float CEXP = 0.12752051393f;
constexpr float DEFER = 62.0f;     // raw-score defer threshold (~e^7.9 bound)

union US8 { unsigned short u[8]; short8 v; };
union UP4 { unsigned int u[4]; short8 v; };

DEVI unsigned short f2bf(float f) {            // fp32 -> bf16 RNE
  unsigned int u = __float_as_uint(f);
  return (unsigned short)((u + 0x7fffu + ((u >> 16) & 1u)) >> 16);
}

DEVI float dq(float x) {                       // int4 quant-dequant, matches ref
  float t = __builtin_rintf(__builtin_fmaf(x, 20.0f, 8.0f));  // round half-even
  t = __builtin_fmaxf(t, 0.0f);
  t = __builtin_fminf(t, 15.0f);
  return (t - 8.0f) * 0.05f;
}

DEVI unsigned short dqb(float x) { return f2bf(dq(x)); }

} // namespace

// ---------------------------------------------------------------------------
// Prepass: dequant K/V -> bf16 ws in MFMA-fragment order.
// Per (bh, tile t of 32 rows), granule g2 = tid (0..511), 8 elems each:
//  K: frag s = g2>>6, lane l = g2&63, elem j:
//       Kd[t*32 + (l&31)][s*16 + (l>>5)*8 + j]
//  V: frag f = g2>>6 (n=f>>1, ks=f&1), lane l, elem j:
//       Vd[t*32 + ks*16 + (l>>5)*8 + j][n*32 + (l&31)]
// These are exactly the A/B fragment mappings of mfma_f32_32x32x16_bf16
// verified in R1-R7 (QK^T swapped A-frag; PV B-frag).
// ---------------------------------------------------------------------------
__global__ __launch_bounds__(512)
void eit3_pre(const float* __restrict__ kg, const float* __restrict__ vg,
              unsigned short* __restrict__ kws, unsigned short* __restrict__ vws)
{
  const int tid = threadIdx.x;
  const int t = blockIdx.x, h = blockIdx.y, b = blockIdx.z;
  const size_t tb = (((size_t)(b * 16 + h)) * NT + t) * TILE_E;
  __shared__ __align__(16) unsigned short KL[32 * 136];  // stride 136: rows 16B-aligned
  __shared__ __align__(16) unsigned short VL[32 * 136];

  // ---- load K/V rows (coalesced), dequant -> bf16, row-major LDS ----
  {
    const int r = tid >> 4, c8 = (tid & 15) * 8;
    const float* ks = kg + ((size_t)b * SK + (size_t)t * KVB + r) * DM + h * DH + c8;
    const float* vs = vg + ((size_t)b * SK + (size_t)t * KVB + r) * DM + h * DH + c8;
    float4 ka = *(const float4*)ks, kb4 = *(const float4*)(ks + 4);
    float4 va = *(const float4*)vs, vb4 = *(const float4*)(vs + 4);
    US8 ok, ov;
    ok.u[0] = dqb(ka.x); ok.u[1] = dqb(ka.y); ok.u[2] = dqb(ka.z); ok.u[3] = dqb(ka.w);
    ok.u[4] = dqb(kb4.x); ok.u[5] = dqb(kb4.y); ok.u[6] = dqb(kb4.z); ok.u[7] = dqb(kb4.w);
    ov.u[0] = dqb(va.x); ov.u[1] = dqb(va.y); ov.u[2] = dqb(va.z); ov.u[3] = dqb(va.w);
    ov.u[4] = dqb(vb4.x); ov.u[5] = dqb(vb4.y); ov.u[6] = dqb(vb4.z); ov.u[7] = dqb(vb4.w);
    *(short8*)(KL + r * 136 + c8) = ok.v;
    *(short8*)(VL + r * 136 + c8) = ov.v;
  }
  __syncthreads();

  const int l = tid & 63;
  const int lq = l & 31, lh = (l >> 5) * 8;
  // ---- K fragment gather (16B-aligned contiguous LDS read per thread) ----
  {
    const int s = tid >> 6;
    short8 o = *(const short8*)(KL + lq * 136 + s * 16 + lh);
    *(short8*)(kws + tb + (size_t)tid * 8) = o;
  }
  // ---- V fragment gather (column walk, scalar u16 reads) ----
  {
    const int f = tid >> 6, n = f >> 1, ks2 = f & 1;
    US8 o;
#pragma unroll
    for (int j = 0; j < 8; ++j)
      o.u[j] = VL[(ks2 * 16 + lh + j) * 136 + n * 32 + lq];
    *(short8*)(vws + tb + (size_t)tid * 8) = o.v;
  }
}

// ---------------------------------------------------------------------------
// Main attention kernel: 4 waves, 32 q-rows/wave, KVB=32, ZERO LDS,
// register-direct fragment loads, no in-loop barriers, K prefetch depth 1.
// ---------------------------------------------------------------------------
__global__ __launch_bounds__(256, 2)
void eit3_attn(const unsigned short* __restrict__ kws,
               const unsigned short* __restrict__ vws,
               const float* __restrict__ qg,
               const unsigned char* __restrict__ maskg,
               const int* __restrict__ qsg, float* __restrict__ outg)
{
  const int tid  = threadIdx.x;
  const int lane = tid & 63;
  const int w    = tid >> 6;        // wave 0..3
  const int hi   = lane >> 5;
  const int ql   = lane & 31;
  const int hi8  = hi * 8;
  // XCD-grouped decode: XCD x owns bh in {8g+x}; the 16 q-blocks of one bh
  // are consecutive slots -> co-resident -> per-tile frag stream is L2-hit.
  const int phys = blockIdx.x;                     // 0..1023
  const int xcd = phys & 7, slot = phys >> 3;      // slot 0..127
  const int bh = 8 * (slot >> 4) + xcd;            // 0..63
  const int qb = slot & 15;                        // 0..15
  const int h = bh & 15, b = bh >> 4;
  const int q0 = qb * 128;
  const long long qstart = (long long)qsg[0];

  // ---- robust all-true mask check (u8 or i32 bool layouts), 8 B/thread ----
  const unsigned char* mrow = maskg + (size_t)b * SK;
  int ok_u8, ok_i32;
  {
    const unsigned int* p = (const unsigned int*)(mrow + tid * 8);
    unsigned int w0 = p[0], w1 = p[1];
    int a0 = (w0 & 0xFFu) && (w0 & 0xFF00u) && (w0 & 0xFF0000u) && (w0 & 0xFF000000u);
    int a1 = (w1 & 0xFFu) && (w1 & 0xFF00u) && (w1 & 0xFF0000u) && (w1 & 0xFF000000u);
    ok_u8  = a0 && a1;
    ok_i32 = (w0 == 1u) && (w1 == 1u);
  }
  const int a_u8  = __syncthreads_and(ok_u8);
  const int a_i32 = __syncthreads_and(ok_i32);
  const bool mask_all = (a_u8 | a_i32) != 0;

  const size_t tbase = (size_t)bh * NT * TILE_E;
  const unsigned short* kb = kws + tbase + lane * 8;
  const unsigned short* vb = vws + tbase + lane * 8;

  // ---- Q fragments (B-operand of swapped QK^T): lane holds Q[q][16s+8hi+i] ----
  short8 qf[8];
  {
    const float* qp = qg + ((size_t)b * SQ + q0 + w * 32 + ql) * DM + h * DH + hi8;
#pragma unroll
    for (int s = 0; s < 8; ++s) {
      float4 fa = *(const float4*)(qp + s * 16);
      float4 fb = *(const float4*)(qp + s * 16 + 4);
      US8 t;
      t.u[0] = f2bf(fa.x); t.u[1] = f2bf(fa.y); t.u[2] = f2bf(fa.z); t.u[3] = f2bf(fa.w);
      t.u[4] = f2bf(fb.x); t.u[5] = f2bf(fb.y); t.u[6] = f2bf(fb.z); t.u[7] = f2bf(fb.w);
      qf[s] = t.v;
    }
  }

  f32x16 zv;
#pragma unroll
  for (int r = 0; r < 16; ++r) zv[r] = 0.0f;
  f32x16 acc[4];
  acc[0] = zv; acc[1] = zv; acc[2] = zv; acc[3] = zv;
  float M = -3.0e38f, L = 0.0f;
  const long long qlim = qstart + (long long)(q0 + w * 32 + ql);

  short8 kfA[8], kfB[8];
  {
#pragma unroll
    for (int s = 0; s < 8; ++s) kfA[s] = *(const short8*)(kb + s * 512);
  }

  // one tile: V-frag loads -> QK^T(kfP) -> prefetch K(t+1)->kfN -> softmax -> PV
  auto step = [&](int t, short8 (&kfP)[8], short8 (&kfN)[8]) {
    const int kv0 = t * KVB;

    // V fragment loads: in flight across QK^T + softmax, consumed by PV
    short8 vf[8];
    {
      const unsigned short* p = vb + (size_t)t * TILE_E;
#pragma unroll
      for (int f = 0; f < 8; ++f) vf[f] = *(const short8*)(p + f * 512);
    }

    // ---- QK^T (swapped): S^T[k][q] = Kd[k][:]·Q[q][:] ----
    f32x16 st = zv;
    __builtin_amdgcn_s_setprio(1);
#pragma unroll
    for (int s = 0; s < 8; ++s)
      st = __builtin_amdgcn_mfma_f32_32x32x16_bf16(kfP[s], qf[s], st, 0, 0, 0);
    __builtin_amdgcn_s_setprio(0);

    // ---- prefetch K(t+1): latency hidden under softmax + PV ----
    {
      const int tn = (t + 1 < NT) ? (t + 1) : (NT - 1);
      const unsigned short* p = kb + (size_t)tn * TILE_E;
#pragma unroll
      for (int s = 0; s < 8; ++s) kfN[s] = *(const short8*)(p + s * 512);
    }

    const bool fast = mask_all && ((long long)(kv0 + KVB - 1) <= qstart + (long long)q0);

    // ---- masking (slow path only; direct global byte loads) ----
    if (!fast) {
#pragma unroll
      for (int r = 0; r < 16; ++r) {
        int nl = (r & 3) + 8 * (r >> 2) + 4 * hi;
        bool ok = (mrow[kv0 + nl] != 0) && ((long long)(kv0 + nl) <= qlim);
        if (!ok) st[r] = -3.0e38f;
      }
    }

    // ---- online softmax (defer-max); verified shfl_xor pair reduce ----
    float t8[8];
#pragma unroll
    for (int i = 0; i < 8; ++i) t8[i] = __builtin_fmaxf(st[i], st[i + 8]);
#pragma unroll
    for (int i = 0; i < 4; ++i) t8[i] = __builtin_fmaxf(t8[i], t8[i + 4]);
    float pmax = __builtin_fmaxf(__builtin_fmaxf(t8[0], t8[1]),
                                 __builtin_fmaxf(t8[2], t8[3]));
    pmax = __builtin_fmaxf(pmax, __shfl_xor(pmax, 32));
    if (!__all(pmax <= M + DEFER)) {        // T13: rescale only on real growth
      float Mn = __builtin_fmaxf(M, pmax);
      float sc = __builtin_amdgcn_exp2f((M - Mn) * CEXP);
      L *= sc;
#pragma unroll
      for (int r = 0; r < 16; ++r) {
        float s2 = __shfl(sc, (r & 3) + 8 * (r >> 2) + 4 * hi);
        acc[0][r] *= s2; acc[1][r] *= s2; acc[2][r] *= s2; acc[3][r] *= s2;
      }
      M = Mn;
    }
#pragma unroll
    for (int r = 0; r < 16; ++r)
      st[r] = __builtin_amdgcn_exp2f((st[r] - M) * CEXP);
    if (!fast) {   // force masked p to exactly 0 (handles all-masked tiles)
#pragma unroll
      for (int r = 0; r < 16; ++r) {
        int nl = (r & 3) + 8 * (r >> 2) + 4 * hi;
        bool ok = (mrow[kv0 + nl] != 0) && ((long long)(kv0 + nl) <= qlim);
        if (!ok) st[r] = 0.0f;
      }
    }
    float s8[8];
#pragma unroll
    for (int i = 0; i < 8; ++i) s8[i] = st[i] + st[i + 8];
#pragma unroll
    for (int i = 0; i < 4; ++i) s8[i] = s8[i] + s8[i + 4];
    float ps = (s8[0] + s8[1]) + (s8[2] + s8[3]);
    ps += __shfl_xor(ps, 32);
    L += ps;

    // ---- P -> bf16 A-frags: cvt_pk pairs + permlane32_swap (T12) ----
    // (safe: X*/Y* hold DISTINCT values, no register-coalescing hazard)
    short8 pa[2];
#pragma unroll
    for (int ks = 0; ks < 2; ++ks) {
      const int m8 = ks * 8;
      unsigned int X0, X1, Y0, Y1;
      asm("v_cvt_pk_bf16_f32 %0, %1, %2" : "=v"(X0) : "v"(st[m8 + 0]), "v"(st[m8 + 1]));
      asm("v_cvt_pk_bf16_f32 %0, %1, %2" : "=v"(X1) : "v"(st[m8 + 2]), "v"(st[m8 + 3]));
      asm("v_cvt_pk_bf16_f32 %0, %1, %2" : "=v"(Y0) : "v"(st[m8 + 4]), "v"(st[m8 + 5]));
      asm("v_cvt_pk_bf16_f32 %0, %1, %2" : "=v"(Y1) : "v"(st[m8 + 6]), "v"(st[m8 + 7]));
      asm("v_permlane32_swap_b32 %0, %1" : "+v"(X0), "+v"(Y0));
      asm("v_permlane32_swap_b32 %0, %1" : "+v"(X1), "+v"(Y1));
      UP4 P;
      P.u[0] = X0; P.u[1] = X1; P.u[2] = Y0; P.u[3] = Y1;
      pa[ks] = P.v;
    }

    // ---- PV: out[q][d] += P[q][k]·Vd[k][d]; B-frags register-direct ----
    __builtin_amdgcn_s_setprio(1);
#pragma unroll
    for (int n = 0; n < 4; ++n) {
#pragma unroll
      for (int ks = 0; ks < 2; ++ks)
        acc[n] = __builtin_amdgcn_mfma_f32_32x32x16_bf16(pa[ks], vf[n * 2 + ks],
                                                         acc[n], 0, 0, 0);
    }
    __builtin_amdgcn_s_setprio(0);
  };

  for (int t = 0; t < NT; t += 2) {   // NT even; no in-loop barriers
    step(t, kfA, kfB);
    step(t + 1, kfB, kfA);
  }

  // ---- epilogue: out = acc / L ----
  if (L == 0.0f) L = 1.0f;
  float rinv = 1.0f / L;
#pragma unroll
  for (int r = 0; r < 16; ++r) {
    int cr = (r & 3) + 8 * (r >> 2) + 4 * hi;
    float inv = __shfl(rinv, cr);
    float* op = outg + ((size_t)b * SQ + q0 + w * 32 + cr) * DM + h * DH + ql;
    op[0]  = acc[0][r] * inv;
    op[32] = acc[1][r] * inv;
    op[64] = acc[2][r] * inv;
    op[96] = acc[3][r] * inv;
  }
}

// ---------------------------------------------------------------------------
// Fallback (R1 kernel, in-kernel dequant) — used only if ws is too small.
// ---------------------------------------------------------------------------
__global__ __launch_bounds__(512, 2)
void eit3_attn_fb(const float* __restrict__ qg, const float* __restrict__ kg,
                  const float* __restrict__ vg, const unsigned char* __restrict__ maskg,
                  const int* __restrict__ qsg, float* __restrict__ outg)
{
  const int tid  = threadIdx.x;
  const int lane = tid & 63;
  const int w    = tid >> 6;
  const int hi   = lane >> 5;
  const int ql   = lane & 31;
  const int qb = blockIdx.x;
  const int h  = blockIdx.y;
  const int b  = blockIdx.z;
  const int q0 = qb * 256;
  const long long qstart = (long long)qsg[0];

  __shared__ __align__(16) unsigned short Ksh[64 * 128];
  __shared__ __align__(16) unsigned short Vsh[64 * 128];
  __shared__ unsigned char mskSh[64];

  const unsigned int vbase = (unsigned int)(size_t)(void*)Vsh;

  const unsigned char* mrow = maskg + (size_t)b * SK;
  int ok_u8, ok_i32;
  {
    const unsigned char* p4 = mrow + tid * 4;
    unsigned char b0 = p4[0], b1 = p4[1], b2 = p4[2], b3 = p4[3];
    ok_u8  = (b0 && b1 && b2 && b3);
    ok_i32 = (b0 && !b1 && !b2 && !b3);
  }
  const int a_u8  = __syncthreads_and(ok_u8);
  const int a_i32 = __syncthreads_and(ok_i32);
  const bool mask_all = (a_u8 | a_i32) != 0;

  short8 qf[8];
  {
    const int qrow = q0 + w * 32 + ql;
    const float* qp = qg + ((size_t)b * SQ + qrow) * DM + h * DH + hi * 8;
#pragma unroll
    for (int s = 0; s < 8; ++s) {
      float4 fa = *(const float4*)(qp + s * 16);
      float4 fb = *(const float4*)(qp + s * 16 + 4);
      US8 t;
      t.u[0] = f2bf(fa.x); t.u[1] = f2bf(fa.y); t.u[2] = f2bf(fa.z); t.u[3] = f2bf(fa.w);
      t.u[4] = f2bf(fb.x); t.u[5] = f2bf(fb.y); t.u[6] = f2bf(fb.z); t.u[7] = f2bf(fb.w);
      qf[s] = t.v;
    }
  }

  f32x16 zv;
#pragma unroll
  for (int r = 0; r < 16; ++r) zv[r] = 0.0f;
  f32x16 acc[4];
  acc[0] = zv; acc[1] = zv; acc[2] = zv; acc[3] = zv;
  float M = -3.0e38f, L = 0.0f;

  const float* kptr = kg + ((size_t)b * SK) * DM + h * DH;
  const float* vptr = vg + ((size_t)b * SK) * DM + h * DH;

  for (int kv0 = 0; kv0 < SK; kv0 += 64) {
    __syncthreads();
#pragma unroll
    for (int j = 0; j < 2; ++j) {
      int idx = tid + 512 * j;
      int n = idx >> 4, d8 = idx & 15;
      const float* gp = kptr + (size_t)(kv0 + n) * DM + d8 * 8;
      float4 fa = *(const float4*)gp;
      float4 fb = *(const float4*)(gp + 4);
      US8 t;
      t.u[0] = dqb(fa.x); t.u[1] = dqb(fa.y); t.u[2] = dqb(fa.z); t.u[3] = dqb(fa.w);
      t.u[4] = dqb(fb.x); t.u[5] = dqb(fb.y); t.u[6] = dqb(fb.z); t.u[7] = dqb(fb.w);
      int ui = (n * 128 + d8 * 8) ^ ((n & 7) << 3);
      *(short8*)(Ksh + ui) = t.v;
    }
    {
      int kr = w * 8 + (lane & 7);
      int c3 = lane >> 3;
#pragma unroll
      for (int j = 0; j < 4; ++j) {
        int d4 = c3 + 8 * j;
        const float* gp = vptr + (size_t)(kv0 + kr) * DM + d4 * 4;
        float4 fa = *(const float4*)gp;
        ushort4 tv;
        tv.x = dqb(fa.x); tv.y = dqb(fa.y); tv.z = dqb(fa.z); tv.w = dqb(fa.w);
        int d = d4 * 4;
        int ui = ((kr >> 2) * 8 + (d >> 4)) * 64 + (kr & 3) * 16 + (d & 15);
        *(ushort4*)(Vsh + ui) = tv;
      }
    }
    const bool causal_ok = ((long long)kv0 + 63) <= (qstart + (long long)q0);
    const bool fast = mask_all && causal_ok;
    if (!fast && w == 0) mskSh[lane] = mrow[kv0 + lane];
    __syncthreads();

    f32x16 st[2];
#pragma unroll
    for (int t = 0; t < 2; ++t) {
      f32x16 sa = zv;
#pragma unroll
      for (int s = 0; s < 8; ++s) {
        int kr = t * 32 + ql;
        int ui = (kr * 128 + s * 16 + hi * 8) ^ ((kr & 7) << 3);
        short8 af = *(const short8*)(Ksh + ui);
        sa = __builtin_amdgcn_mfma_f32_32x32x16_bf16(af, qf[s], sa, 0, 0, 0);
      }
      st[t] = sa;
    }
    if (!fast) {
      const long long qlim = qstart + (long long)(q0 + w * 32 + ql);
#pragma unroll
      for (int t = 0; t < 2; ++t) {
#pragma unroll
        for (int r = 0; r < 16; ++r) {
          int nl = t * 32 + (r & 3) + 8 * (r >> 2) + 4 * hi;
          bool ok = (mskSh[nl] != 0) && ((long long)(kv0 + nl) <= qlim);
          if (!ok) st[t][r] = -3.0e38f;
        }
      }
    }
    f32x16 red;
#pragma unroll
    for (int r = 0; r < 16; ++r) red[r] = __builtin_fmaxf(st[0][r], st[1][r]);
#pragma unroll
    for (int r = 0; r < 8; ++r) red[r] = __builtin_fmaxf(red[r], red[r + 8]);
#pragma unroll
    for (int r = 0; r < 4; ++r) red[r] = __builtin_fmaxf(red[r], red[r + 4]);
    float pmax = __builtin_fmaxf(__builtin_fmaxf(red[0], red[1]),
                                 __builtin_fmaxf(red[2], red[3]));
    pmax = __builtin_fmaxf(pmax, __shfl_xor(pmax, 32));
    const float Mnew = __builtin_fmaxf(M, pmax);
    const float scale = __builtin_amdgcn_exp2f((M - Mnew) * CEXP);
#pragma unroll
    for (int t = 0; t < 2; ++t) {
#pragma unroll
      for (int r = 0; r < 16; ++r)
        st[t][r] = __builtin_amdgcn_exp2f((st[t][r] - Mnew) * CEXP);
    }
    if (!fast) {
      const long long qlim = qstart + (long long)(q0 + w * 32 + ql);
#pragma unroll
      for (int t = 0; t < 2; ++t) {
#pragma unroll
        for (int r = 0; r < 16; ++r) {
          int nl = t * 32 + (r & 3) + 8 * (r >> 2) + 4 * hi;
          bool ok = (mskSh[nl] != 0) && ((long long)(kv0 + nl) <= qlim);
          if (!ok) st[t][r] = 0.0f;
        }
      }
    }
    f32x16 sx;
#pragma unroll
    for (int r = 0; r < 16; ++r) sx[r] = st[0][r] + st[1][r];
#pragma unroll
    for (int r = 0; r < 8; ++r) sx[r] = sx[r] + sx[r + 8];
#pragma unroll
    for (int r = 0; r < 4; ++r) sx[r] = sx[r] + sx[r + 4];
    float ps = (sx[0] + sx[1]) + (sx[2] + sx[3]);
    ps += __shfl_xor(ps, 32);
    L = L * scale + ps;
    if (!__all(Mnew == M)) {
#pragma unroll
      for (int r = 0; r < 16; ++r) {
        float sc = __shfl(scale, (r & 3) + 8 * (r >> 2) + 4 * hi);
        acc[0][r] *= sc; acc[1][r] *= sc; acc[2][r] *= sc; acc[3][r] *= sc;
      }
    }
    M = Mnew;

    short8 pa[4];
#pragma unroll
    for (int ks = 0; ks < 4; ++ks) {
      const int t = ks >> 1;
      const int m8 = (ks & 1) * 8;
      unsigned int X0, X1, Y0, Y1;
      asm("v_cvt_pk_bf16_f32 %0, %1, %2" : "=v"(X0) : "v"(st[t][m8 + 0]), "v"(st[t][m8 + 1]));
      asm("v_cvt_pk_bf16_f32 %0, %1, %2" : "=v"(X1) : "v"(st[t][m8 + 2]), "v"(st[t][m8 + 3]));
      asm("v_cvt_pk_bf16_f32 %0, %1, %2" : "=v"(Y0) : "v"(st[t][m8 + 4]), "v"(st[t][m8 + 5]));
      asm("v_cvt_pk_bf16_f32 %0, %1, %2" : "=v"(Y1) : "v"(st[t][m8 + 6]), "v"(st[t][m8 + 7]));
      asm("v_permlane32_swap_b32 %0, %1" : "+v"(X0), "+v"(Y0));
      asm("v_permlane32_swap_b32 %0, %1" : "+v"(X1), "+v"(Y1));
      UP4 P;
      P.u[0] = X0; P.u[1] = X1; P.u[2] = Y0; P.u[3] = Y1;
      pa[ks] = P.v;
    }
#pragma unroll
    for (int n = 0; n < 4; ++n) {
      unsigned long long t0[4], t1[4];
#pragma unroll
      for (int ks = 0; ks < 4; ++ks) {
        unsigned int addr = vbase
          + (unsigned int)(((4 * ks + 2 * hi) * 8 + 2 * n + ((lane >> 4) & 1)) * 128)
          + (unsigned int)((lane & 15) * 8);
        asm volatile("ds_read_b64_tr_b16 %0, %1" : "=v"(t0[ks]) : "v"(addr));
        asm volatile("ds_read_b64_tr_b16 %0, %1 offset:1024" : "=v"(t1[ks]) : "v"(addr));
      }
      asm volatile("s_waitcnt lgkmcnt(0)" ::: "memory");
      __builtin_amdgcn_sched_barrier(0);
#pragma unroll
      for (int ks = 0; ks < 4; ++ks) {
        union { unsigned long long q[2]; short8 v; } vb2;
        vb2.q[0] = t0[ks]; vb2.q[1] = t1[ks];
        acc[n] = __builtin_amdgcn_mfma_f32_32x32x16_bf16(pa[ks], vb2.v, acc[n], 0, 0, 0);
      }
    }
  }

  if (L == 0.0f) L = 1.0f;
  float rinv = 1.0f / L;
#pragma unroll
  for (int r = 0; r < 16; ++r) {
    int cr = (r & 3) + 8 * (r >> 2) + 4 * hi;
    float inv = __shfl(rinv, cr);
    float* op = outg + ((size_t)b * SQ + (q0 + w * 32 + cr)) * DM + h * DH + ql;
    op[0]  = acc[0][r] * inv;
    op[32] = acc[1][r] * inv;
    op[64] = acc[2][r] * inv;
    op[96] = acc[3][r] * inv;
  }
}

extern "C" void kernel_launch(void* const* d_in, const int* in_sizes, int n_in,
                              void* d_out, int out_size, void* d_ws, size_t ws_size,
                              hipStream_t stream) {
  (void)in_sizes; (void)n_in; (void)out_size;
  const float* q = (const float*)d_in[0];
  const float* k = (const float*)d_in[1];
  const float* v = (const float*)d_in[2];
  const unsigned char* mask = (const unsigned char*)d_in[3];
  const int* qs = (const int*)d_in[4];

  const size_t need = (size_t)2 * 16777216 * 2;   // K + V bf16 = 64 MiB
  if (ws_size >= need) {
    unsigned short* kws = (unsigned short*)d_ws;
    unsigned short* vws = kws + 16777216;
    dim3 pgrid(NT, 16, 4);
    eit3_pre<<<pgrid, dim3(512), 0, stream>>>(k, v, kws, vws);
    eit3_attn<<<dim3(1024), dim3(256), 0, stream>>>(kws, vws, q, mask, qs, (float*)d_out);
  } else {
    dim3 grid(SQ / 256, 16, 4);
    eit3_attn_fb<<<grid, dim3(512), 0, stream>>>(q, k, v, mask, qs, (float*)d_out);
  }
}

// Round 9
// 216.424 us; speedup vs baseline: 1.0207x; 1.0207x over previous
//
#include <hip/hip_runtime.h>

// EIT3Attention: B=4, Sq=Sk=2048, d_model=2048, H=16, Dh=128, fp32 I/O.
// R9: 1-wave blocks (grid 4096), 3 waves/SIMD via __launch_bounds__(64,3)
// (reg budget <=170: acc 64 + qf 32 + K/V time-shared 32 + st 16 + temps).
// M==0 fixed softmax base (no max tree / rescale; CEXP folded into Q so
// p = exp2(st) directly). Fragment-order ws (R8 prepass), no LDS, no barriers.
// R8 lesson: stalls (~35% of cycles) at 2 waves/SIMD were the binder, not LDS.

typedef __attribute__((ext_vector_type(8))) short short8;
typedef __attribute__((ext_vector_type(16))) float f32x16;

#define DEVI __device__ __forceinline__

namespace {

constexpr int DM = 2048;   // d_model
constexpr int SQ = 2048;
constexpr int SK = 2048;
constexpr int DH = 128;
constexpr int KVB = 32;            // kv rows per tile
constexpr int NT = SK / KVB;       // 64 tiles
constexpr int TILE_E = KVB * DH;   // 4096 elems per tensor-tile
// (1/sqrt(128)) * log2(e), folded into Q at conversion
constexpr float CEXP = 0.12752051393f;

union US8 { unsigned short u[8]; short8 v; };
union UP4 { unsigned int u[4]; short8 v; };

DEVI unsigned short f2bf(float f) {            // fp32 -> bf16 RNE
  unsigned int u = __float_as_uint(f);
  return (unsigned short)((u + 0x7fffu + ((u >> 16) & 1u)) >> 16);
}

DEVI float dq(float x) {                       // int4 quant-dequant, matches ref
  float t = __builtin_rintf(__builtin_fmaf(x, 20.0f, 8.0f));  // round half-even
  t = __builtin_fmaxf(t, 0.0f);
  t = __builtin_fminf(t, 15.0f);
  return (t - 8.0f) * 0.05f;
}

DEVI unsigned short dqb(float x) { return f2bf(dq(x)); }

} // namespace

// ---------------------------------------------------------------------------
// Prepass (verified R8): dequant K/V -> bf16 ws in MFMA-fragment order.
// Per (bh, tile t of 32 rows), granule g2 = tid (0..511), 8 elems each:
//  K: frag s = g2>>6, lane l = g2&63: Kd[t*32 + (l&31)][s*16 + (l>>5)*8 + j]
//  V: frag f = g2>>6 (n=f>>1, ks=f&1): Vd[t*32 + ks*16 + (l>>5)*8 + j][n*32 + (l&31)]
// ---------------------------------------------------------------------------
__global__ __launch_bounds__(512)
void eit3_pre(const float* __restrict__ kg, const float* __restrict__ vg,
              unsigned short* __restrict__ kws, unsigned short* __restrict__ vws)
{
  const int tid = threadIdx.x;
  const int t = blockIdx.x, h = blockIdx.y, b = blockIdx.z;
  const size_t tb = (((size_t)(b * 16 + h)) * NT + t) * TILE_E;
  __shared__ __align__(16) unsigned short KL[32 * 136];  // rows 16B-aligned
  __shared__ __align__(16) unsigned short VL[32 * 136];

  {
    const int r = tid >> 4, c8 = (tid & 15) * 8;
    const float* ks = kg + ((size_t)b * SK + (size_t)t * KVB + r) * DM + h * DH + c8;
    const float* vs = vg + ((size_t)b * SK + (size_t)t * KVB + r) * DM + h * DH + c8;
    float4 ka = *(const float4*)ks, kb4 = *(const float4*)(ks + 4);
    float4 va = *(const float4*)vs, vb4 = *(const float4*)(vs + 4);
    US8 ok, ov;
    ok.u[0] = dqb(ka.x); ok.u[1] = dqb(ka.y); ok.u[2] = dqb(ka.z); ok.u[3] = dqb(ka.w);
    ok.u[4] = dqb(kb4.x); ok.u[5] = dqb(kb4.y); ok.u[6] = dqb(kb4.z); ok.u[7] = dqb(kb4.w);
    ov.u[0] = dqb(va.x); ov.u[1] = dqb(va.y); ov.u[2] = dqb(va.z); ov.u[3] = dqb(va.w);
    ov.u[4] = dqb(vb4.x); ov.u[5] = dqb(vb4.y); ov.u[6] = dqb(vb4.z); ov.u[7] = dqb(vb4.w);
    *(short8*)(KL + r * 136 + c8) = ok.v;
    *(short8*)(VL + r * 136 + c8) = ov.v;
  }
  __syncthreads();

  const int l = tid & 63;
  const int lq = l & 31, lh = (l >> 5) * 8;
  {
    const int s = tid >> 6;
    short8 o = *(const short8*)(KL + lq * 136 + s * 16 + lh);
    *(short8*)(kws + tb + (size_t)tid * 8) = o;
  }
  {
    const int f = tid >> 6, n = f >> 1, ks2 = f & 1;
    US8 o;
#pragma unroll
    for (int j = 0; j < 8; ++j)
      o.u[j] = VL[(ks2 * 16 + lh + j) * 136 + n * 32 + lq];
    *(short8*)(vws + tb + (size_t)tid * 8) = o.v;
  }
}

// ---------------------------------------------------------------------------
// Main attention kernel: 1 wave per block, 32 q-rows, KVB=32, zero LDS,
// M==0 softmax, K/V register time-share, 3 waves/SIMD target.
// ---------------------------------------------------------------------------
__global__ __launch_bounds__(64, 3)
void eit3_attn(const unsigned short* __restrict__ kws,
               const unsigned short* __restrict__ vws,
               const float* __restrict__ qg,
               const unsigned char* __restrict__ maskg,
               const int* __restrict__ qsg, float* __restrict__ outg)
{
  const int lane = threadIdx.x;
  const int hi   = lane >> 5;
  const int ql   = lane & 31;
  const int hi8  = hi * 8;
  // XCD-grouped decode: XCD x owns bh in {8g+x}; all 64 wave-blocks of a bh
  // (16 qb x 4 w) are consecutive slots -> co-resident -> L2-hit streams.
  const int phys = blockIdx.x;                     // 0..4095
  const int xcd = phys & 7, slot = phys >> 3;      // slot 0..511
  const int bh  = 8 * (slot >> 6) + xcd;           // 0..63
  const int sub = slot & 63;
  const int q0  = (sub >> 2) * 128 + (sub & 3) * 32;   // 32-row q tile
  const int h = bh & 15, b = bh >> 4;
  const long long qstart = (long long)qsg[0];

  // ---- wave-level all-true mask check (u8 or i32 bool layouts), 32 B/lane ----
  const unsigned char* mrow = maskg + (size_t)b * SK;
  int ok_u8 = 1, ok_i32 = 1;
  {
    const unsigned int* p = (const unsigned int*)(mrow + lane * 32);
#pragma unroll
    for (int j = 0; j < 8; ++j) {
      unsigned int x = p[j];
      int a = (x & 0xFFu) && (x & 0xFF00u) && (x & 0xFF0000u) && (x & 0xFF000000u);
      ok_u8 &= a;
      ok_i32 &= (x == 1u);
    }
  }
  const bool mask_all = __all(ok_u8) || __all(ok_i32);

  const size_t tbase = (size_t)bh * NT * TILE_E;
  const unsigned short* kb = kws + tbase + lane * 8;
  const unsigned short* vb = vws + tbase + lane * 8;

  // ---- Q fragments, CEXP pre-folded: lane holds (Q*CEXP)[q0+ql][16s+8hi+j] ----
  short8 qf[8];
  {
    const float* qp = qg + ((size_t)b * SQ + q0 + ql) * DM + h * DH + hi8;
#pragma unroll
    for (int s = 0; s < 8; ++s) {
      float4 fa = *(const float4*)(qp + s * 16);
      float4 fb = *(const float4*)(qp + s * 16 + 4);
      US8 t;
      t.u[0] = f2bf(fa.x * CEXP); t.u[1] = f2bf(fa.y * CEXP);
      t.u[2] = f2bf(fa.z * CEXP); t.u[3] = f2bf(fa.w * CEXP);
      t.u[4] = f2bf(fb.x * CEXP); t.u[5] = f2bf(fb.y * CEXP);
      t.u[6] = f2bf(fb.z * CEXP); t.u[7] = f2bf(fb.w * CEXP);
      qf[s] = t.v;
    }
  }

  f32x16 zv;
#pragma unroll
  for (int r = 0; r < 16; ++r) zv[r] = 0.0f;
  f32x16 acc[4];
  acc[0] = zv; acc[1] = zv; acc[2] = zv; acc[3] = zv;
  float L = 0.0f;
  const long long qlim = qstart + (long long)(q0 + ql);

  for (int t = 0; t < NT; ++t) {
    const int kv0 = t * KVB;

    // ---- K fragments into the time-shared block ----
    short8 kv[8];
    {
      const unsigned short* p = kb + (size_t)t * TILE_E;
#pragma unroll
      for (int s = 0; s < 8; ++s) kv[s] = *(const short8*)(p + s * 512);
    }

    // ---- QK^T (swapped): st[k][q] = (Kd[k][:]) . (Q*CEXP)[q][:] ----
    f32x16 st = zv;
    __builtin_amdgcn_s_setprio(1);
#pragma unroll
    for (int s = 0; s < 8; ++s)
      st = __builtin_amdgcn_mfma_f32_32x32x16_bf16(kv[s], qf[s], st, 0, 0, 0);
    __builtin_amdgcn_s_setprio(0);

    // ---- V fragments overwrite the same block (WAR handled by compiler) ----
    {
      const unsigned short* p = vb + (size_t)t * TILE_E;
#pragma unroll
      for (int f = 0; f < 8; ++f) kv[f] = *(const short8*)(p + f * 512);
    }

    const bool fast = mask_all && ((long long)(kv0 + KVB - 1) <= qstart + (long long)q0);

    // ---- masking (slow path only) ----
    if (!fast) {
#pragma unroll
      for (int r = 0; r < 16; ++r) {
        int nl = (r & 3) + 8 * (r >> 2) + 4 * hi;
        bool ok = (mrow[kv0 + nl] != 0) && ((long long)(kv0 + nl) <= qlim);
        if (!ok) st[r] = -3.0e38f;
      }
    }

    // ---- p = exp2(st)  (M == 0; st pre-scaled; bounded: |st| <= ~80) ----
#pragma unroll
    for (int r = 0; r < 16; ++r)
      st[r] = __builtin_amdgcn_exp2f(st[r]);
    // masked entries: exp2(-3e38) == 0, no explicit zeroing needed

    // ---- L += sum_k p ----
    float s8[8];
#pragma unroll
    for (int i = 0; i < 8; ++i) s8[i] = st[i] + st[i + 8];
#pragma unroll
    for (int i = 0; i < 4; ++i) s8[i] = s8[i] + s8[i + 4];
    float ps = (s8[0] + s8[1]) + (s8[2] + s8[3]);
    ps += __shfl_xor(ps, 32);
    L += ps;

    // ---- P -> bf16 A-frags: cvt_pk pairs + permlane32_swap (T12) ----
    short8 pa[2];
#pragma unroll
    for (int ks = 0; ks < 2; ++ks) {
      const int m8 = ks * 8;
      unsigned int X0, X1, Y0, Y1;
      asm("v_cvt_pk_bf16_f32 %0, %1, %2" : "=v"(X0) : "v"(st[m8 + 0]), "v"(st[m8 + 1]));
      asm("v_cvt_pk_bf16_f32 %0, %1, %2" : "=v"(X1) : "v"(st[m8 + 2]), "v"(st[m8 + 3]));
      asm("v_cvt_pk_bf16_f32 %0, %1, %2" : "=v"(Y0) : "v"(st[m8 + 4]), "v"(st[m8 + 5]));
      asm("v_cvt_pk_bf16_f32 %0, %1, %2" : "=v"(Y1) : "v"(st[m8 + 6]), "v"(st[m8 + 7]));
      asm("v_permlane32_swap_b32 %0, %1" : "+v"(X0), "+v"(Y0));
      asm("v_permlane32_swap_b32 %0, %1" : "+v"(X1), "+v"(Y1));
      UP4 P;
      P.u[0] = X0; P.u[1] = X1; P.u[2] = Y0; P.u[3] = Y1;
      pa[ks] = P.v;
    }

    // ---- PV: out[q][d] += P[q][k] . Vd[k][d]; B-frags from shared block ----
    __builtin_amdgcn_s_setprio(1);
#pragma unroll
    for (int n = 0; n < 4; ++n) {
#pragma unroll
      for (int ks = 0; ks < 2; ++ks)
        acc[n] = __builtin_amdgcn_mfma_f32_32x32x16_bf16(pa[ks], kv[n * 2 + ks],
                                                         acc[n], 0, 0, 0);
    }
    __builtin_amdgcn_s_setprio(0);
  }

  // ---- epilogue: out = acc / L ----
  if (L == 0.0f) L = 1.0f;
  float rinv = 1.0f / L;
#pragma unroll
  for (int r = 0; r < 16; ++r) {
    int cr = (r & 3) + 8 * (r >> 2) + 4 * hi;
    float inv = __shfl(rinv, cr);
    float* op = outg + ((size_t)b * SQ + q0 + cr) * DM + h * DH + ql;
    op[0]  = acc[0][r] * inv;
    op[32] = acc[1][r] * inv;
    op[64] = acc[2][r] * inv;
    op[96] = acc[3][r] * inv;
  }
}

// ---------------------------------------------------------------------------
// Fallback (R1 kernel, in-kernel dequant) — used only if ws is too small.
// ---------------------------------------------------------------------------
__global__ __launch_bounds__(512, 2)
void eit3_attn_fb(const float* __restrict__ qg, const float* __restrict__ kg,
                  const float* __restrict__ vg, const unsigned char* __restrict__ maskg,
                  const int* __restrict__ qsg, float* __restrict__ outg)
{
  const int tid  = threadIdx.x;
  const int lane = tid & 63;
  const int w    = tid >> 6;
  const int hi   = lane >> 5;
  const int ql   = lane & 31;
  const int qb = blockIdx.x;
  const int h  = blockIdx.y;
  const int b  = blockIdx.z;
  const int q0 = qb * 256;
  const long long qstart = (long long)qsg[0];

  __shared__ __align__(16) unsigned short Ksh[64 * 128];
  __shared__ __align__(16) unsigned short Vsh[64 * 128];
  __shared__ unsigned char mskSh[64];

  const unsigned int vbase = (unsigned int)(size_t)(void*)Vsh;

  const unsigned char* mrow = maskg + (size_t)b * SK;
  int ok_u8, ok_i32;
  {
    const unsigned char* p4 = mrow + tid * 4;
    unsigned char b0 = p4[0], b1 = p4[1], b2 = p4[2], b3 = p4[3];
    ok_u8  = (b0 && b1 && b2 && b3);
    ok_i32 = (b0 && !b1 && !b2 && !b3);
  }
  const int a_u8  = __syncthreads_and(ok_u8);
  const int a_i32 = __syncthreads_and(ok_i32);
  const bool mask_all = (a_u8 | a_i32) != 0;

  short8 qf[8];
  {
    const int qrow = q0 + w * 32 + ql;
    const float* qp = qg + ((size_t)b * SQ + qrow) * DM + h * DH + hi * 8;
#pragma unroll
    for (int s = 0; s < 8; ++s) {
      float4 fa = *(const float4*)(qp + s * 16);
      float4 fb = *(const float4*)(qp + s * 16 + 4);
      US8 t;
      t.u[0] = f2bf(fa.x); t.u[1] = f2bf(fa.y); t.u[2] = f2bf(fa.z); t.u[3] = f2bf(fa.w);
      t.u[4] = f2bf(fb.x); t.u[5] = f2bf(fb.y); t.u[6] = f2bf(fb.z); t.u[7] = f2bf(fb.w);
      qf[s] = t.v;
    }
  }

  f32x16 zv;
#pragma unroll
  for (int r = 0; r < 16; ++r) zv[r] = 0.0f;
  f32x16 acc[4];
  acc[0] = zv; acc[1] = zv; acc[2] = zv; acc[3] = zv;
  float M = -3.0e38f, L = 0.0f;

  const float* kptr = kg + ((size_t)b * SK) * DM + h * DH;
  const float* vptr = vg + ((size_t)b * SK) * DM + h * DH;

  constexpr float CEXP2 = 0.12752051393f;
  for (int kv0 = 0; kv0 < SK; kv0 += 64) {
    __syncthreads();
#pragma unroll
    for (int j = 0; j < 2; ++j) {
      int idx = tid + 512 * j;
      int n = idx >> 4, d8 = idx & 15;
      const float* gp = kptr + (size_t)(kv0 + n) * DM + d8 * 8;
      float4 fa = *(const float4*)gp;
      float4 fb = *(const float4*)(gp + 4);
      US8 t;
      t.u[0] = dqb(fa.x); t.u[1] = dqb(fa.y); t.u[2] = dqb(fa.z); t.u[3] = dqb(fa.w);
      t.u[4] = dqb(fb.x); t.u[5] = dqb(fb.y); t.u[6] = dqb(fb.z); t.u[7] = dqb(fb.w);
      int ui = (n * 128 + d8 * 8) ^ ((n & 7) << 3);
      *(short8*)(Ksh + ui) = t.v;
    }
    {
      int kr = w * 8 + (lane & 7);
      int c3 = lane >> 3;
#pragma unroll
      for (int j = 0; j < 4; ++j) {
        int d4 = c3 + 8 * j;
        const float* gp = vptr + (size_t)(kv0 + kr) * DM + d4 * 4;
        float4 fa = *(const float4*)gp;
        ushort4 tv;
        tv.x = dqb(fa.x); tv.y = dqb(fa.y); tv.z = dqb(fa.z); tv.w = dqb(fa.w);
        int d = d4 * 4;
        int ui = ((kr >> 2) * 8 + (d >> 4)) * 64 + (kr & 3) * 16 + (d & 15);
        *(ushort4*)(Vsh + ui) = tv;
      }
    }
    const bool causal_ok = ((long long)kv0 + 63) <= (qstart + (long long)q0);
    const bool fast = mask_all && causal_ok;
    if (!fast && w == 0) mskSh[lane] = mrow[kv0 + lane];
    __syncthreads();

    f32x16 st[2];
#pragma unroll
    for (int t = 0; t < 2; ++t) {
      f32x16 sa = zv;
#pragma unroll
      for (int s = 0; s < 8; ++s) {
        int kr = t * 32 + ql;
        int ui = (kr * 128 + s * 16 + hi * 8) ^ ((kr & 7) << 3);
        short8 af = *(const short8*)(Ksh + ui);
        sa = __builtin_amdgcn_mfma_f32_32x32x16_bf16(af, qf[s], sa, 0, 0, 0);
      }
      st[t] = sa;
    }
    if (!fast) {
      const long long qlim = qstart + (long long)(q0 + w * 32 + ql);
#pragma unroll
      for (int t = 0; t < 2; ++t) {
#pragma unroll
        for (int r = 0; r < 16; ++r) {
          int nl = t * 32 + (r & 3) + 8 * (r >> 2) + 4 * hi;
          bool ok = (mskSh[nl] != 0) && ((long long)(kv0 + nl) <= qlim);
          if (!ok) st[t][r] = -3.0e38f;
        }
      }
    }
    f32x16 red;
#pragma unroll
    for (int r = 0; r < 16; ++r) red[r] = __builtin_fmaxf(st[0][r], st[1][r]);
#pragma unroll
    for (int r = 0; r < 8; ++r) red[r] = __builtin_fmaxf(red[r], red[r + 8]);
#pragma unroll
    for (int r = 0; r < 4; ++r) red[r] = __builtin_fmaxf(red[r], red[r + 4]);
    float pmax = __builtin_fmaxf(__builtin_fmaxf(red[0], red[1]),
                                 __builtin_fmaxf(red[2], red[3]));
    pmax = __builtin_fmaxf(pmax, __shfl_xor(pmax, 32));
    const float Mnew = __builtin_fmaxf(M, pmax);
    const float scale = __builtin_amdgcn_exp2f((M - Mnew) * CEXP2);
#pragma unroll
    for (int t = 0; t < 2; ++t) {
#pragma unroll
      for (int r = 0; r < 16; ++r)
        st[t][r] = __builtin_amdgcn_exp2f((st[t][r] - Mnew) * CEXP2);
    }
    if (!fast) {
      const long long qlim = qstart + (long long)(q0 + w * 32 + ql);
#pragma unroll
      for (int t = 0; t < 2; ++t) {
#pragma unroll
        for (int r = 0; r < 16; ++r) {
          int nl = t * 32 + (r & 3) + 8 * (r >> 2) + 4 * hi;
          bool ok = (mskSh[nl] != 0) && ((long long)(kv0 + nl) <= qlim);
          if (!ok) st[t][r] = 0.0f;
        }
      }
    }
    f32x16 sx;
#pragma unroll
    for (int r = 0; r < 16; ++r) sx[r] = st[0][r] + st[1][r];
#pragma unroll
    for (int r = 0; r < 8; ++r) sx[r] = sx[r] + sx[r + 8];
#pragma unroll
    for (int r = 0; r < 4; ++r) sx[r] = sx[r] + sx[r + 4];
    float ps = (sx[0] + sx[1]) + (sx[2] + sx[3]);
    ps += __shfl_xor(ps, 32);
    L = L * scale + ps;
    if (!__all(Mnew == M)) {
#pragma unroll
      for (int r = 0; r < 16; ++r) {
        float sc = __shfl(scale, (r & 3) + 8 * (r >> 2) + 4 * hi);
        acc[0][r] *= sc; acc[1][r] *= sc; acc[2][r] *= sc; acc[3][r] *= sc;
      }
    }
    M = Mnew;

    short8 pa[4];
#pragma unroll
    for (int ks = 0; ks < 4; ++ks) {
      const int t = ks >> 1;
      const int m8 = (ks & 1) * 8;
      unsigned int X0, X1, Y0, Y1;
      asm("v_cvt_pk_bf16_f32 %0, %1, %2" : "=v"(X0) : "v"(st[t][m8 + 0]), "v"(st[t][m8 + 1]));
      asm("v_cvt_pk_bf16_f32 %0, %1, %2" : "=v"(X1) : "v"(st[t][m8 + 2]), "v"(st[t][m8 + 3]));
      asm("v_cvt_pk_bf16_f32 %0, %1, %2" : "=v"(Y0) : "v"(st[t][m8 + 4]), "v"(st[t][m8 + 5]));
      asm("v_cvt_pk_bf16_f32 %0, %1, %2" : "=v"(Y1) : "v"(st[t][m8 + 6]), "v"(st[t][m8 + 7]));
      asm("v_permlane32_swap_b32 %0, %1" : "+v"(X0), "+v"(Y0));
      asm("v_permlane32_swap_b32 %0, %1" : "+v"(X1), "+v"(Y1));
      UP4 P;
      P.u[0] = X0; P.u[1] = X1; P.u[2] = Y0; P.u[3] = Y1;
      pa[ks] = P.v;
    }
#pragma unroll
    for (int n = 0; n < 4; ++n) {
      unsigned long long t0[4], t1[4];
#pragma unroll
      for (int ks = 0; ks < 4; ++ks) {
        unsigned int addr = vbase
          + (unsigned int)(((4 * ks + 2 * hi) * 8 + 2 * n + ((lane >> 4) & 1)) * 128)
          + (unsigned int)((lane & 15) * 8);
        asm volatile("ds_read_b64_tr_b16 %0, %1" : "=v"(t0[ks]) : "v"(addr));
        asm volatile("ds_read_b64_tr_b16 %0, %1 offset:1024" : "=v"(t1[ks]) : "v"(addr));
      }
      asm volatile("s_waitcnt lgkmcnt(0)" ::: "memory");
      __builtin_amdgcn_sched_barrier(0);
#pragma unroll
      for (int ks = 0; ks < 4; ++ks) {
        union { unsigned long long q[2]; short8 v; } vb2;
        vb2.q[0] = t0[ks]; vb2.q[1] = t1[ks];
        acc[n] = __builtin_amdgcn_mfma_f32_32x32x16_bf16(pa[ks], vb2.v, acc[n], 0, 0, 0);
      }
    }
  }

  if (L == 0.0f) L = 1.0f;
  float rinv = 1.0f / L;
#pragma unroll
  for (int r = 0; r < 16; ++r) {
    int cr = (r & 3) + 8 * (r >> 2) + 4 * hi;
    float inv = __shfl(rinv, cr);
    float* op = outg + ((size_t)b * SQ + (q0 + w * 32 + cr)) * DM + h * DH + ql;
    op[0]  = acc[0][r] * inv;
    op[32] = acc[1][r] * inv;
    op[64] = acc[2][r] * inv;
    op[96] = acc[3][r] * inv;
  }
}

extern "C" void kernel_launch(void* const* d_in, const int* in_sizes, int n_in,
                              void* d_out, int out_size, void* d_ws, size_t ws_size,
                              hipStream_t stream) {
  (void)in_sizes; (void)n_in; (void)out_size;
  const float* q = (const float*)d_in[0];
  const float* k = (const float*)d_in[1];
  const float* v = (const float*)d_in[2];
  const unsigned char* mask = (const unsigned char*)d_in[3];
  const int* qs = (const int*)d_in[4];

  const size_t need = (size_t)2 * 16777216 * 2;   // K + V bf16 = 64 MiB
  if (ws_size >= need) {
    unsigned short* kws = (unsigned short*)d_ws;
    unsigned short* vws = kws + 16777216;
    dim3 pgrid(NT, 16, 4);
    eit3_pre<<<pgrid, dim3(512), 0, stream>>>(k, v, kws, vws);
    eit3_attn<<<dim3(4096), dim3(64), 0, stream>>>(kws, vws, q, mask, qs, (float*)d_out);
  } else {
    dim3 grid(SQ / 256, 16, 4);
    eit3_attn_fb<<<grid, dim3(512), 0, stream>>>(q, k, v, mask, qs, (float*)d_out);
  }
}